// Round 1
// baseline (152.968 us; speedup 1.0000x reference)
//
#include <hip/hip_runtime.h>
#include <math.h>

// TransR scoring: out[b] = -|| proj[r[b]] @ (ent[h[b]] - ent[t[b]]) + rel[r[b]] ||
//
// Strategy: one block per relation (1000 blocks). Each block:
//   1. scans r[] (32 KB, L2-resident) and compacts its batch indices into LDS
//   2. for each chunk of up to 16 items:
//      a. stages D[j][:] = ent[h]-ent[t] (16 KB LDS)
//      b. streams M = proj[relid] in 8 tiles of 32 rows x 256 (32 KB LDS each),
//         coalesced float4 loads, XOR-swizzled rows for conflict-free compute reads
//      c. thread (rt,g) computes diff rows rt of items {g, g+8}; shfl-reduce the
//         squared diffs over the 32 row-lanes; accumulate in registers across tiles
//   3. out[b] = -sqrt(sum_sq)
// proj is read exactly once per relation -> ~280 MB total HBM traffic.

#define ED   256   // entity/relation dim
#define NCH  16    // items per chunk
#define TR   32    // M rows per tile
#define CAP  2048  // max items per relation we can hold (8192 total / huge margin)

__global__ __launch_bounds__(256, 1)
void transr_score_kernel(const int* __restrict__ h, const int* __restrict__ r,
                         const int* __restrict__ t, const float* __restrict__ ent,
                         const float* __restrict__ rel, const float* __restrict__ proj,
                         float* __restrict__ out, int B)
{
    __shared__ int   items[CAP];                    // 8 KB
    __shared__ int   s_n;
    __shared__ __align__(16) float D[NCH][ED];      // 16 KB
    __shared__ __align__(16) float Mt[TR][ED];      // 32 KB
    __shared__ float remb[ED];                      // 1 KB
    __shared__ float sacc[NCH];

    const int relid = blockIdx.x;
    const int tid   = threadIdx.x;

    if (tid == 0) s_n = 0;
    __syncthreads();

    // ---- compact batch indices whose relation == relid (order irrelevant) ----
    for (int i0 = tid * 4; i0 < B; i0 += 256 * 4) {
        int4 rv = *(const int4*)(r + i0);
        if (rv.x == relid) { int p = atomicAdd(&s_n, 1); if (p < CAP) items[p] = i0;     }
        if (rv.y == relid) { int p = atomicAdd(&s_n, 1); if (p < CAP) items[p] = i0 + 1; }
        if (rv.z == relid) { int p = atomicAdd(&s_n, 1); if (p < CAP) items[p] = i0 + 2; }
        if (rv.w == relid) { int p = atomicAdd(&s_n, 1); if (p < CAP) items[p] = i0 + 3; }
    }
    remb[tid] = rel[(size_t)relid * ED + tid];
    __syncthreads();

    int n = s_n < CAP ? s_n : CAP;
    if (n == 0) return;

    const float* Mg = proj + (size_t)relid * (ED * ED);

    const int rt = tid & 31;   // row within tile
    const int g  = tid >> 5;   // item group 0..7 -> items {g, g+8}
    const int sw = rt & 7;     // bank-quad swizzle for this row

    for (int c0 = 0; c0 < n; c0 += NCH) {
        const int nc = min(NCH, n - c0);

        // ---- stage D[j][:] = ent[h[b]] - ent[t[b]] (zeros for j >= nc) ----
        {
            const int j  = tid >> 4;   // 0..15
            const int e4 = tid & 15;   // float4 column base
            if (j < nc) {
                const int b = items[c0 + j];
                const float4* hv = (const float4*)(ent + (size_t)h[b] * ED);
                const float4* tv = (const float4*)(ent + (size_t)t[b] * ED);
                #pragma unroll
                for (int k = 0; k < 4; ++k) {
                    float4 a = hv[e4 + 16 * k];
                    float4 c = tv[e4 + 16 * k];
                    float4 d4; d4.x = a.x - c.x; d4.y = a.y - c.y;
                               d4.z = a.z - c.z; d4.w = a.w - c.w;
                    *(float4*)&D[j][4 * (e4 + 16 * k)] = d4;
                }
            } else {
                float4 z; z.x = z.y = z.z = z.w = 0.f;
                #pragma unroll
                for (int k = 0; k < 4; ++k) *(float4*)&D[j][4 * (e4 + 16 * k)] = z;
            }
        }
        __syncthreads();

        float sq0 = 0.f, sq1 = 0.f;   // only lane rt==0 of each half-wave keeps these

        for (int tile = 0; tile < 8; ++tile) {
            // ---- stage Mt (coalesced global float4; XOR-swizzled LDS rows) ----
            {
                const float4* Mg4 = (const float4*)(Mg + (size_t)tile * TR * ED);
                #pragma unroll
                for (int k = 0; k < 8; ++k) {
                    int f  = tid + 256 * k;        // 0..2047
                    int rr = f >> 6, e4 = f & 63;
                    *(float4*)&Mt[rr][4 * (e4 ^ (rr & 7))] = Mg4[f];
                }
            }
            __syncthreads();

            float acc0 = 0.f, acc1 = 0.f;
            #pragma unroll 8
            for (int e4 = 0; e4 < 64; ++e4) {
                float4 m  = *(const float4*)&Mt[rt][4 * (e4 ^ sw)];
                float4 d0 = *(const float4*)&D[g][4 * e4];
                float4 d1 = *(const float4*)&D[g + 8][4 * e4];
                acc0 = fmaf(m.x, d0.x, acc0); acc0 = fmaf(m.y, d0.y, acc0);
                acc0 = fmaf(m.z, d0.z, acc0); acc0 = fmaf(m.w, d0.w, acc0);
                acc1 = fmaf(m.x, d1.x, acc1); acc1 = fmaf(m.y, d1.y, acc1);
                acc1 = fmaf(m.z, d1.z, acc1); acc1 = fmaf(m.w, d1.w, acc1);
            }

            const int row = tile * TR + rt;
            const float rb = remb[row];
            float s0 = acc0 + rb; s0 *= s0;
            float s1 = acc1 + rb; s1 *= s1;
            // reduce squared diffs over the 32 row-lanes of this half-wave
            #pragma unroll
            for (int off = 16; off >= 1; off >>= 1) {
                s0 += __shfl_xor(s0, off, 32);
                s1 += __shfl_xor(s1, off, 32);
            }
            sq0 += s0;   // total only valid at rt==0; harmless elsewhere
            sq1 += s1;
            __syncthreads();   // Mt reused next tile
        }

        // one unique writer per sacc slot (half-wave rt==0)
        if (rt == 0) { sacc[g] = sq0; sacc[g + 8] = sq1; }
        __syncthreads();

        if (tid < nc) out[items[c0 + tid]] = -sqrtf(sacc[tid]);
        // no barrier needed before next chunk's D staging: next sacc write is
        // separated from this read by the D-staging + 8 tile barriers
        __syncthreads();
    }
}

extern "C" void kernel_launch(void* const* d_in, const int* in_sizes, int n_in,
                              void* d_out, int out_size, void* d_ws, size_t ws_size,
                              hipStream_t stream)
{
    const int*   h    = (const int*)d_in[0];
    const int*   r    = (const int*)d_in[1];
    const int*   t    = (const int*)d_in[2];
    const float* ent  = (const float*)d_in[3];
    const float* rel  = (const float*)d_in[4];
    const float* proj = (const float*)d_in[5];
    float*       out  = (float*)d_out;

    const int B  = in_sizes[0];
    const int NR = in_sizes[5] / (ED * ED);   // number of relations

    transr_score_kernel<<<NR, 256, 0, stream>>>(h, r, t, ent, rel, proj, out, B);
}

// Round 2
// 107.160 us; speedup vs baseline: 1.4275x; 1.4275x over previous
//
#include <hip/hip_runtime.h>
#include <math.h>

// TransR scoring: out[b] = -|| proj[r[b]] @ (ent[h[b]] - ent[t[b]]) + rel[r[b]] ||
//
// Round-2 structure (parallelism fix — round 1 was latency-bound at 10% HBM BW):
//   K1 prep  : CSR build (relation -> item list, fixed-stride CAP=64) +
//              D[b][:] = ent[h[b]] - ent[t[b]] precomputed into ws (8 MB).
//   K2 partial: grid (NR=1000, NT=8). Block (rel,tile) stages rows
//              [32*tile, 32*tile+32) of proj[rel] (32 KB LDS, XOR-swizzled),
//              stages D rows for <=16 items per chunk, computes the 32
//              diff-rows' squared contributions, shfl-reduces over 32 lanes,
//              writes part[b*8+tile]. Fixed slots -> bitwise deterministic.
//   K3 final : out[b] = -sqrt(sum of 8 partials in fixed order).
// proj read exactly once (262 MB); 8000 main blocks @ 49.4 KB LDS = 3 blocks/CU.

#define ED   256   // entity/relation dim
#define E4   64    // float4s per row
#define NCH  16    // items per chunk
#define TR   32    // M rows per tile
#define NT   8     // row tiles per relation (256/TR)
#define CAP  64    // max items per relation (B=8192, p=1/1000 -> P(n>64) ~ 1e-35)

// ---------------- K1: CSR + D precompute ----------------
__global__ void transr_prep_kernel(const int* __restrict__ h, const int* __restrict__ r,
                                   const int* __restrict__ t, const float* __restrict__ ent,
                                   int B, int nbCsr,
                                   int* __restrict__ counts, int* __restrict__ itemsG,
                                   float4* __restrict__ Dws)
{
    const int tid = threadIdx.x;
    if ((int)blockIdx.x < nbCsr) {
        int i = blockIdx.x * 256 + tid;
        if (i < B) {
            int rv  = r[i];
            int pos = atomicAdd(&counts[rv], 1);
            if (pos < CAP) itemsG[rv * CAP + pos] = i;
        }
    } else {
        int i = ((int)blockIdx.x - nbCsr) * 256 + tid;   // float4 index
        if (i < B * E4) {
            int b = i >> 6, e4 = i & 63;
            const float4* hv = (const float4*)ent + (size_t)h[b] * E4;
            const float4* tv = (const float4*)ent + (size_t)t[b] * E4;
            float4 a = hv[e4], c = tv[e4];
            float4 d; d.x = a.x - c.x; d.y = a.y - c.y; d.z = a.z - c.z; d.w = a.w - c.w;
            Dws[i] = d;
        }
    }
}

// ---------------- K2: per-(relation, row-tile) partial sums ----------------
__global__ __launch_bounds__(256, 1)
void transr_partial_kernel(const float* __restrict__ rel, const float* __restrict__ proj,
                           const int* __restrict__ counts, const int* __restrict__ itemsG,
                           const float4* __restrict__ Dws, float* __restrict__ part)
{
    __shared__ int items_s[CAP];                    // 256 B
    __shared__ __align__(16) float Mt[TR][ED];      // 32 KB
    __shared__ __align__(16) float Dsh[NCH][ED];    // 16 KB

    const int relid = blockIdx.x;
    const int tile  = blockIdx.y;
    const int tid   = threadIdx.x;

    const int n = min(counts[relid], CAP);
    if (n == 0) return;
    if (tid < CAP) items_s[tid] = (tid < n) ? itemsG[relid * CAP + tid] : 0;

    // stage Mt = proj[relid] rows [tile*32 .. tile*32+32), XOR-swizzled per row.
    // Each wave writes one dense 1 KB row per k -> conflict-free staging.
    {
        const float4* Mg4 = (const float4*)(proj + (size_t)relid * ED * ED
                                                 + (size_t)tile * TR * ED);
        #pragma unroll
        for (int k = 0; k < 8; ++k) {
            int f  = tid + 256 * k;          // 0..2047
            int rr = f >> 6, e4 = f & 63;
            *(float4*)&Mt[rr][4 * (e4 ^ (rr & 7))] = Mg4[f];
        }
    }

    const int rt = tid & 31;                 // row within tile
    const int g  = tid >> 5;                 // item group: items {g, g+8}
    const int sw = rt & 7;
    const float rb = rel[(size_t)relid * ED + tile * TR + rt];

    __syncthreads();                         // covers Mt + items_s

    for (int c0 = 0; c0 < n; c0 += NCH) {
        // stage Dsh rows c0..c0+15 (linear layout; each wave writes dense 1 KB
        // rows, and the global side reads one item's contiguous 1 KB -> coalesced)
        #pragma unroll
        for (int k = 0; k < 4; ++k) {
            int f  = tid + 256 * k;          // 0..1023
            int j  = f >> 6;                 // 0..15
            int e4 = f & 63;
            float4 v;
            if (c0 + j < n) v = Dws[(size_t)items_s[c0 + j] * E4 + e4];
            else { v.x = v.y = v.z = v.w = 0.f; }
            *(float4*)&Dsh[j][4 * e4] = v;
        }
        __syncthreads();

        float acc0 = 0.f, acc1 = 0.f;
        #pragma unroll 8
        for (int e4 = 0; e4 < 64; ++e4) {
            float4 m  = *(const float4*)&Mt[rt][4 * (e4 ^ sw)];
            float4 d0 = *(const float4*)&Dsh[g][4 * e4];       // broadcast (32 lanes)
            float4 d1 = *(const float4*)&Dsh[g + 8][4 * e4];   // broadcast
            acc0 = fmaf(m.x, d0.x, acc0); acc0 = fmaf(m.y, d0.y, acc0);
            acc0 = fmaf(m.z, d0.z, acc0); acc0 = fmaf(m.w, d0.w, acc0);
            acc1 = fmaf(m.x, d1.x, acc1); acc1 = fmaf(m.y, d1.y, acc1);
            acc1 = fmaf(m.z, d1.z, acc1); acc1 = fmaf(m.w, d1.w, acc1);
        }

        float s0 = acc0 + rb; s0 *= s0;
        float s1 = acc1 + rb; s1 *= s1;
        #pragma unroll
        for (int off = 16; off >= 1; off >>= 1) {
            s0 += __shfl_xor(s0, off, 32);
            s1 += __shfl_xor(s1, off, 32);
        }
        if (rt == 0) {   // fixed (item,tile) slot -> deterministic
            if (c0 + g     < n) part[(size_t)items_s[c0 + g]     * NT + tile] = s0;
            if (c0 + g + 8 < n) part[(size_t)items_s[c0 + g + 8] * NT + tile] = s1;
        }
        __syncthreads();                     // Dsh reused next chunk
    }
}

// ---------------- K3: finalize ----------------
__global__ void transr_finalize_kernel(const float* __restrict__ part,
                                       float* __restrict__ out, int B)
{
    int i = blockIdx.x * 256 + threadIdx.x;
    if (i < B) {
        const float4* p = (const float4*)(part + (size_t)i * NT);
        float4 a = p[0], b = p[1];
        out[i] = -sqrtf(a.x + a.y + a.z + a.w + b.x + b.y + b.z + b.w);
    }
}

// ---------------- fallback: round-1 single kernel (proven correct) ----------------
#define FNCH 16
#define FCAP 2048
__global__ __launch_bounds__(256, 1)
void transr_score_kernel(const int* __restrict__ h, const int* __restrict__ r,
                         const int* __restrict__ t, const float* __restrict__ ent,
                         const float* __restrict__ rel, const float* __restrict__ proj,
                         float* __restrict__ out, int B)
{
    __shared__ int   items[FCAP];
    __shared__ int   s_n;
    __shared__ __align__(16) float D[FNCH][ED];
    __shared__ __align__(16) float Mt[TR][ED];
    __shared__ float remb[ED];
    __shared__ float sacc[FNCH];

    const int relid = blockIdx.x;
    const int tid   = threadIdx.x;

    if (tid == 0) s_n = 0;
    __syncthreads();

    for (int i0 = tid * 4; i0 < B; i0 += 256 * 4) {
        int4 rv = *(const int4*)(r + i0);
        if (rv.x == relid) { int p = atomicAdd(&s_n, 1); if (p < FCAP) items[p] = i0;     }
        if (rv.y == relid) { int p = atomicAdd(&s_n, 1); if (p < FCAP) items[p] = i0 + 1; }
        if (rv.z == relid) { int p = atomicAdd(&s_n, 1); if (p < FCAP) items[p] = i0 + 2; }
        if (rv.w == relid) { int p = atomicAdd(&s_n, 1); if (p < FCAP) items[p] = i0 + 3; }
    }
    remb[tid] = rel[(size_t)relid * ED + tid];
    __syncthreads();

    int n = s_n < FCAP ? s_n : FCAP;
    if (n == 0) return;

    const float* Mg = proj + (size_t)relid * (ED * ED);
    const int rt = tid & 31;
    const int g  = tid >> 5;
    const int sw = rt & 7;

    for (int c0 = 0; c0 < n; c0 += FNCH) {
        const int nc = min(FNCH, n - c0);
        {
            const int j  = tid >> 4;
            const int e4 = tid & 15;
            if (j < nc) {
                const int b = items[c0 + j];
                const float4* hv = (const float4*)(ent + (size_t)h[b] * ED);
                const float4* tv = (const float4*)(ent + (size_t)t[b] * ED);
                #pragma unroll
                for (int k = 0; k < 4; ++k) {
                    float4 a = hv[e4 + 16 * k];
                    float4 c = tv[e4 + 16 * k];
                    float4 d4; d4.x = a.x - c.x; d4.y = a.y - c.y;
                               d4.z = a.z - c.z; d4.w = a.w - c.w;
                    *(float4*)&D[j][4 * (e4 + 16 * k)] = d4;
                }
            } else {
                float4 z; z.x = z.y = z.z = z.w = 0.f;
                #pragma unroll
                for (int k = 0; k < 4; ++k) *(float4*)&D[j][4 * (e4 + 16 * k)] = z;
            }
        }
        __syncthreads();

        float sq0 = 0.f, sq1 = 0.f;
        for (int tile = 0; tile < 8; ++tile) {
            {
                const float4* Mg4 = (const float4*)(Mg + (size_t)tile * TR * ED);
                #pragma unroll
                for (int k = 0; k < 8; ++k) {
                    int f  = tid + 256 * k;
                    int rr = f >> 6, e4 = f & 63;
                    *(float4*)&Mt[rr][4 * (e4 ^ (rr & 7))] = Mg4[f];
                }
            }
            __syncthreads();

            float acc0 = 0.f, acc1 = 0.f;
            #pragma unroll 8
            for (int e4 = 0; e4 < 64; ++e4) {
                float4 m  = *(const float4*)&Mt[rt][4 * (e4 ^ sw)];
                float4 d0 = *(const float4*)&D[g][4 * e4];
                float4 d1 = *(const float4*)&D[g + 8][4 * e4];
                acc0 = fmaf(m.x, d0.x, acc0); acc0 = fmaf(m.y, d0.y, acc0);
                acc0 = fmaf(m.z, d0.z, acc0); acc0 = fmaf(m.w, d0.w, acc0);
                acc1 = fmaf(m.x, d1.x, acc1); acc1 = fmaf(m.y, d1.y, acc1);
                acc1 = fmaf(m.z, d1.z, acc1); acc1 = fmaf(m.w, d1.w, acc1);
            }

            const int row = tile * TR + rt;
            const float rb = remb[row];
            float s0 = acc0 + rb; s0 *= s0;
            float s1 = acc1 + rb; s1 *= s1;
            #pragma unroll
            for (int off = 16; off >= 1; off >>= 1) {
                s0 += __shfl_xor(s0, off, 32);
                s1 += __shfl_xor(s1, off, 32);
            }
            sq0 += s0;
            sq1 += s1;
            __syncthreads();
        }

        if (rt == 0) { sacc[g] = sq0; sacc[g + 8] = sq1; }
        __syncthreads();
        if (tid < nc) out[items[c0 + tid]] = -sqrtf(sacc[tid]);
        __syncthreads();
    }
}

// ---------------- launch ----------------
extern "C" void kernel_launch(void* const* d_in, const int* in_sizes, int n_in,
                              void* d_out, int out_size, void* d_ws, size_t ws_size,
                              hipStream_t stream)
{
    const int*   h    = (const int*)d_in[0];
    const int*   r    = (const int*)d_in[1];
    const int*   t    = (const int*)d_in[2];
    const float* ent  = (const float*)d_in[3];
    const float* rel  = (const float*)d_in[4];
    const float* proj = (const float*)d_in[5];
    float*       out  = (float*)d_out;

    const int B  = in_sizes[0];
    const int NR = in_sizes[5] / (ED * ED);

    // workspace layout (256 B aligned chunks)
    size_t o_counts = 0;
    size_t o_items  = (o_counts + (size_t)NR * 4 + 255) & ~(size_t)255;
    size_t o_part   = (o_items + (size_t)NR * CAP * 4 + 255) & ~(size_t)255;
    size_t o_D      = (o_part + (size_t)B * NT * 4 + 255) & ~(size_t)255;
    size_t need     = o_D + (size_t)B * ED * 4;

    if (ws_size >= need) {
        int*    counts = (int*)((char*)d_ws + o_counts);
        int*    itemsG = (int*)((char*)d_ws + o_items);
        float*  part   = (float*)((char*)d_ws + o_part);
        float4* Dws    = (float4*)((char*)d_ws + o_D);

        hipMemsetAsync(counts, 0, (size_t)NR * 4, stream);

        const int nbCsr = (B + 255) / 256;
        const int nbD   = (B * E4 + 255) / 256;
        transr_prep_kernel<<<nbCsr + nbD, 256, 0, stream>>>(h, r, t, ent, B, nbCsr,
                                                            counts, itemsG, Dws);
        transr_partial_kernel<<<dim3(NR, NT), 256, 0, stream>>>(rel, proj, counts,
                                                                itemsG, Dws, part);
        transr_finalize_kernel<<<(B + 255) / 256, 256, 0, stream>>>(part, out, B);
    } else {
        transr_score_kernel<<<NR, 256, 0, stream>>>(h, r, t, ent, rel, proj, out, B);
    }
}

// Round 3
// 62.967 us; speedup vs baseline: 2.4293x; 1.7018x over previous
//
#include <hip/hip_runtime.h>
#include <math.h>

// TransR scoring: out[b] = -|| proj[r[b]] @ (ent[h[b]] - ent[t[b]]) + rel[r[b]] ||
//
// Round-3: MFMA path. Round 2 was LDS/VALU-bound (3 B LDS per FLOP in the fp32
// matvec loop -> HBM stuck at 2.5 TB/s). Per relation the batched matvec is a
// GEMM C[256x16] = M[256x256] x D[256x16]; mfma_f32_16x16x32_bf16 needs only
// 0.125 B LDS per FLOP. bf16 error projects onto the diff direction: ~0.01
// absolute on out, threshold is 0.137.
//
//   K1 prep    : CSR (relation -> items, CAP=64) + D[b] = ent[h]-ent[t] in bf16 (4 MB ws)
//   K2 partial : grid (NR, 4). Block (rel,tile) stages 64 rows of M as bf16 in
//                LDS (XOR-swizzled 16B chunks), 16-item chunks of D, 8 MFMAs per
//                wave, epilogue: +r_emb, square, shfl reduce over row groups,
//                cross-wave LDS reduce -> part[b*4+tile]. Deterministic slots.
//   K3 final   : out[b] = -sqrt(part[b][0..3] summed in fixed order)

#define ED   256
#define TR64 64    // M rows per block
#define NT   4     // row tiles (256/64)
#define CAP  64    // max items per relation (P(n>64) ~ 1e-35 at B=8192,NR=1000)

typedef __attribute__((ext_vector_type(8))) short bf16x8;
typedef __attribute__((ext_vector_type(4))) float f32x4;

__device__ __forceinline__ unsigned int bfbits_rne(float x) {
    unsigned int u = __builtin_bit_cast(unsigned int, x);
    return (u + 0x7fffu + ((u >> 16) & 1u)) >> 16;
}
__device__ __forceinline__ unsigned int pack2(float x, float y) {
    return bfbits_rne(x) | (bfbits_rne(y) << 16);
}

// ---------------- K1: CSR + D precompute (bf16) ----------------
__global__ void transr_prep_kernel(const int* __restrict__ h, const int* __restrict__ r,
                                   const int* __restrict__ t, const float* __restrict__ ent,
                                   int B, int nbCsr,
                                   int* __restrict__ counts, int* __restrict__ itemsG,
                                   uint4* __restrict__ Dbf)
{
    const int tid = threadIdx.x;
    if ((int)blockIdx.x < nbCsr) {
        int i = blockIdx.x * 256 + tid;
        if (i < B) {
            int rv  = r[i];
            int pos = atomicAdd(&counts[rv], 1);
            if (pos < CAP) itemsG[rv * CAP + pos] = i;
        }
    } else {
        int i = ((int)blockIdx.x - nbCsr) * 256 + tid;   // 16B-chunk id (8 bf16)
        if (i < B * 32) {
            int b = i >> 5, c = i & 31;
            const float4* hv = (const float4*)ent + (size_t)h[b] * 64 + c * 2;
            const float4* tv = (const float4*)ent + (size_t)t[b] * 64 + c * 2;
            float4 a0 = hv[0], a1 = hv[1], b0 = tv[0], b1 = tv[1];
            uint4 o;
            o.x = pack2(a0.x - b0.x, a0.y - b0.y);
            o.y = pack2(a0.z - b0.z, a0.w - b0.w);
            o.z = pack2(a1.x - b1.x, a1.y - b1.y);
            o.w = pack2(a1.z - b1.z, a1.w - b1.w);
            Dbf[i] = o;
        }
    }
}

// ---------------- K2: MFMA partial sums ----------------
__global__ __launch_bounds__(256, 2)
void transr_mfma_kernel(const float* __restrict__ rel, const float* __restrict__ proj,
                        const int* __restrict__ counts, const int* __restrict__ itemsG,
                        const uint4* __restrict__ Dbf, float* __restrict__ part)
{
    __shared__ __align__(16) unsigned short Mt[TR64 * ED];  // 32 KB bf16
    __shared__ __align__(16) unsigned short Dt[16 * ED];    // 8 KB bf16
    __shared__ float remb_s[TR64];
    __shared__ float sacc[4][16];
    __shared__ int   items_s[CAP];

    const int relid = blockIdx.x;
    const int tile  = blockIdx.y;
    const int tid   = threadIdx.x;

    const int n = min(counts[relid], CAP);
    if (n == 0) return;

    if (tid < CAP) items_s[tid] = (tid < n) ? itemsG[relid * CAP + tid] : 0;
    if (tid < TR64) remb_s[tid] = rel[(size_t)relid * ED + tile * TR64 + tid];

    // stage M tile: 64 rows x 256 fp32 -> bf16, 16B chunks XOR-swizzled by row
    {
        const float4* Mg4 = (const float4*)(proj + (size_t)relid * ED * ED
                                                 + (size_t)tile * TR64 * ED);
        #pragma unroll
        for (int it = 0; it < 8; ++it) {
            int f  = tid + 256 * it;         // 0..2047 (64 rows x 32 chunks)
            int rr = f >> 5, c = f & 31;
            float4 a = Mg4[2 * f], b = Mg4[2 * f + 1];
            uint4 o;
            o.x = pack2(a.x, a.y); o.y = pack2(a.z, a.w);
            o.z = pack2(b.x, b.y); o.w = pack2(b.z, b.w);
            *(uint4*)&Mt[rr * ED + ((c ^ (rr & 7)) << 3)] = o;
        }
    }

    const int l  = tid & 63;           // lane
    const int w  = tid >> 6;           // wave 0..3 -> rows w*16..w*16+15
    const int li = l & 15;             // A row within 16 / B item col
    const int lk = l >> 4;             // k-group 0..3
    const int arow = w * 16 + li;
    const int aswz = arow & 7, bswz = li & 7;

    for (int c0 = 0; c0 < n; c0 += 16) {
        // stage D chunk: 16 items x 256 bf16 (zeros for padding)
        #pragma unroll
        for (int it = 0; it < 2; ++it) {
            int f = tid + 256 * it;          // 0..511
            int j = f >> 5, c = f & 31;
            uint4 v = {0u, 0u, 0u, 0u};
            if (c0 + j < n) v = Dbf[(size_t)items_s[c0 + j] * 32 + c];
            *(uint4*)&Dt[j * ED + ((c ^ (j & 7)) << 3)] = v;
        }
        __syncthreads();   // covers Mt/items/remb on first iter, Dt every iter

        f32x4 acc = {0.f, 0.f, 0.f, 0.f};
        #pragma unroll
        for (int kk = 0; kk < 8; ++kk) {
            int c = kk * 4 + lk;             // 16B chunk within row for this k-slice
            bf16x8 av = *(const bf16x8*)&Mt[arow * ED + ((c ^ aswz) << 3)];
            bf16x8 bv = *(const bf16x8*)&Dt[li * ED + ((c ^ bswz) << 3)];
            acc = __builtin_amdgcn_mfma_f32_16x16x32_bf16(av, bv, acc, 0, 0, 0);
        }

        // epilogue: C[row][item] at col=l&15, row=(l>>4)*4+reg (m89-verified)
        float s = 0.f;
        #pragma unroll
        for (int j = 0; j < 4; ++j) {
            float v = acc[j] + remb_s[w * 16 + lk * 4 + j];
            s = fmaf(v, v, s);
        }
        s += __shfl_xor(s, 16);
        s += __shfl_xor(s, 32);              // sum over the 4 k-groups (rows)
        if (l < 16) sacc[w][l] = s;
        __syncthreads();

        if (tid < 16 && c0 + tid < n) {
            part[(size_t)items_s[c0 + tid] * NT + tile] =
                sacc[0][tid] + sacc[1][tid] + sacc[2][tid] + sacc[3][tid];
        }
    }
}

// ---------------- K3: finalize ----------------
__global__ void transr_finalize_kernel(const float* __restrict__ part,
                                       float* __restrict__ out, int B)
{
    int i = blockIdx.x * 256 + threadIdx.x;
    if (i < B) {
        float4 p = *(const float4*)(part + (size_t)i * NT);
        out[i] = -sqrtf(p.x + p.y + p.z + p.w);
    }
}

// ---------------- fallback (round-1, proven): used only if ws too small ----------------
#define FNCH 16
#define FCAP 2048
__global__ __launch_bounds__(256, 1)
void transr_score_kernel(const int* __restrict__ h, const int* __restrict__ r,
                         const int* __restrict__ t, const float* __restrict__ ent,
                         const float* __restrict__ rel, const float* __restrict__ proj,
                         float* __restrict__ out, int B)
{
    __shared__ int   items[FCAP];
    __shared__ int   s_n;
    __shared__ __align__(16) float D[FNCH][ED];
    __shared__ __align__(16) float Mt2[32][ED];
    __shared__ float remb[ED];
    __shared__ float sacc2[FNCH];

    const int relid = blockIdx.x;
    const int tid   = threadIdx.x;
    if (tid == 0) s_n = 0;
    __syncthreads();

    for (int i0 = tid * 4; i0 < B; i0 += 256 * 4) {
        int4 rv = *(const int4*)(r + i0);
        if (rv.x == relid) { int p = atomicAdd(&s_n, 1); if (p < FCAP) items[p] = i0;     }
        if (rv.y == relid) { int p = atomicAdd(&s_n, 1); if (p < FCAP) items[p] = i0 + 1; }
        if (rv.z == relid) { int p = atomicAdd(&s_n, 1); if (p < FCAP) items[p] = i0 + 2; }
        if (rv.w == relid) { int p = atomicAdd(&s_n, 1); if (p < FCAP) items[p] = i0 + 3; }
    }
    remb[tid] = rel[(size_t)relid * ED + tid];
    __syncthreads();

    int n = s_n < FCAP ? s_n : FCAP;
    if (n == 0) return;

    const float* Mg = proj + (size_t)relid * (ED * ED);
    const int rt = tid & 31, g = tid >> 5, sw = rt & 7;

    for (int c0 = 0; c0 < n; c0 += FNCH) {
        const int nc = min(FNCH, n - c0);
        {
            const int j  = tid >> 4;
            const int e4 = tid & 15;
            if (j < nc) {
                const int b = items[c0 + j];
                const float4* hv = (const float4*)(ent + (size_t)h[b] * ED);
                const float4* tv = (const float4*)(ent + (size_t)t[b] * ED);
                #pragma unroll
                for (int k = 0; k < 4; ++k) {
                    float4 a = hv[e4 + 16 * k];
                    float4 c = tv[e4 + 16 * k];
                    float4 d4; d4.x = a.x - c.x; d4.y = a.y - c.y;
                               d4.z = a.z - c.z; d4.w = a.w - c.w;
                    *(float4*)&D[j][4 * (e4 + 16 * k)] = d4;
                }
            } else {
                float4 z; z.x = z.y = z.z = z.w = 0.f;
                #pragma unroll
                for (int k = 0; k < 4; ++k) *(float4*)&D[j][4 * (e4 + 16 * k)] = z;
            }
        }
        __syncthreads();

        float sq0 = 0.f, sq1 = 0.f;
        for (int tile = 0; tile < 8; ++tile) {
            const float4* Mg4 = (const float4*)(Mg + (size_t)tile * 32 * ED);
            #pragma unroll
            for (int k = 0; k < 8; ++k) {
                int f = tid + 256 * k;
                int rr = f >> 6, e4 = f & 63;
                *(float4*)&Mt2[rr][4 * (e4 ^ (rr & 7))] = Mg4[f];
            }
            __syncthreads();

            float acc0 = 0.f, acc1 = 0.f;
            #pragma unroll 8
            for (int e4 = 0; e4 < 64; ++e4) {
                float4 m  = *(const float4*)&Mt2[rt][4 * (e4 ^ sw)];
                float4 d0 = *(const float4*)&D[g][4 * e4];
                float4 d1 = *(const float4*)&D[g + 8][4 * e4];
                acc0 = fmaf(m.x, d0.x, acc0); acc0 = fmaf(m.y, d0.y, acc0);
                acc0 = fmaf(m.z, d0.z, acc0); acc0 = fmaf(m.w, d0.w, acc0);
                acc1 = fmaf(m.x, d1.x, acc1); acc1 = fmaf(m.y, d1.y, acc1);
                acc1 = fmaf(m.z, d1.z, acc1); acc1 = fmaf(m.w, d1.w, acc1);
            }
            const float rb = remb[tile * 32 + rt];
            float s0 = acc0 + rb; s0 *= s0;
            float s1 = acc1 + rb; s1 *= s1;
            #pragma unroll
            for (int off = 16; off >= 1; off >>= 1) {
                s0 += __shfl_xor(s0, off, 32);
                s1 += __shfl_xor(s1, off, 32);
            }
            sq0 += s0; sq1 += s1;
            __syncthreads();
        }
        if (rt == 0) { sacc2[g] = sq0; sacc2[g + 8] = sq1; }
        __syncthreads();
        if (tid < nc) out[items[c0 + tid]] = -sqrtf(sacc2[tid]);
        __syncthreads();
    }
}

// ---------------- launch ----------------
extern "C" void kernel_launch(void* const* d_in, const int* in_sizes, int n_in,
                              void* d_out, int out_size, void* d_ws, size_t ws_size,
                              hipStream_t stream)
{
    const int*   h    = (const int*)d_in[0];
    const int*   r    = (const int*)d_in[1];
    const int*   t    = (const int*)d_in[2];
    const float* ent  = (const float*)d_in[3];
    const float* rel  = (const float*)d_in[4];
    const float* proj = (const float*)d_in[5];
    float*       out  = (float*)d_out;

    const int B  = in_sizes[0];
    const int NR = in_sizes[5] / (ED * ED);

    size_t o_counts = 0;
    size_t o_items  = (o_counts + (size_t)NR * 4 + 255) & ~(size_t)255;
    size_t o_part   = (o_items + (size_t)NR * CAP * 4 + 255) & ~(size_t)255;
    size_t o_D      = (o_part + (size_t)B * NT * 4 + 255) & ~(size_t)255;
    size_t need     = o_D + (size_t)B * ED * 2;   // bf16 D

    if (ws_size >= need) {
        int*   counts = (int*)((char*)d_ws + o_counts);
        int*   itemsG = (int*)((char*)d_ws + o_items);
        float* part   = (float*)((char*)d_ws + o_part);
        uint4* Dbf    = (uint4*)((char*)d_ws + o_D);

        hipMemsetAsync(counts, 0, (size_t)NR * 4, stream);

        const int nbCsr = (B + 255) / 256;
        const int nbD   = (B * 32 + 255) / 256;
        transr_prep_kernel<<<nbCsr + nbD, 256, 0, stream>>>(h, r, t, ent, B, nbCsr,
                                                            counts, itemsG, Dbf);
        transr_mfma_kernel<<<dim3(NR, NT), 256, 0, stream>>>(rel, proj, counts,
                                                             itemsG, Dbf, part);
        transr_finalize_kernel<<<(B + 255) / 256, 256, 0, stream>>>(part, out, B);
    } else {
        transr_score_kernel<<<NR, 256, 0, stream>>>(h, r, t, ent, rel, proj, out, B);
    }
}